// Round 4
// baseline (2115.960 us; speedup 1.0000x reference)
//
#include <hip/hip_runtime.h>

#define FDIM 128
#define NEDGE 640000
#define NNODE 10000
#define K1PAD 160   // edge MLP layer-1 padded K (128 s + 20 rbf + 12 zero)
#define HSTR 136    // LDS h-tile row stride in bf16 elems (272B = 17*16B, aligned)

typedef __attribute__((ext_vector_type(8))) short short8;   // 8 x bf16 (4 VGPRs)
typedef __attribute__((ext_vector_type(4))) float f32x4;
typedef __attribute__((ext_vector_type(4))) unsigned short ushort4_t;

static __device__ __forceinline__ unsigned short f2bf(float f){
  unsigned int u = __builtin_bit_cast(unsigned int, f);
  u += 0x7fffu + ((u >> 16) & 1u);           // RNE
  return (unsigned short)(u >> 16);
}
static __device__ __forceinline__ short8 pack8(const float* x){
  short8 r;
#pragma unroll
  for (int i = 0; i < 8; ++i) r[i] = (short)f2bf(x[i]);
  return r;
}
static __device__ __forceinline__ short8 cvt8(float4 a, float4 b){
  float x[8] = {a.x, a.y, a.z, a.w, b.x, b.y, b.z, b.w};
  return pack8(x);
}
static __device__ __forceinline__ f32x4 mfma16(short8 a, short8 b, f32x4 c){
  return __builtin_amdgcn_mfma_f32_16x16x32_bf16(a, b, c, 0, 0, 0);
}
static __device__ __forceinline__ float silu(float p){
  return p * (1.f / (1.f + __expf(-p)));
}

// ---------------- prep: transpose + bf16-convert all 8 weight matrices ----------------
__global__ __launch_bounds__(256) void prep_wt(
    const float* __restrict__ ms_w1, const float* __restrict__ mv_w1,
    const float* __restrict__ ms_w2, const float* __restrict__ mv_w2,
    const float* __restrict__ us_w1, const float* __restrict__ uv_w1,
    const float* __restrict__ us_w2, const float* __restrict__ uv_w2,
    unsigned short* __restrict__ wbuf)
{
  int i = blockIdx.x * 256 + threadIdx.x;
  if (i >= 172032) return;
  float val;
  if (i < 40960) {                       // W1T edge MLPs, K=148 pad 160
    int t = (i < 20480) ? i : i - 20480;
    const float* src = (i < 20480) ? ms_w1 : mv_w1;
    int j = t / 160, k = t - j * 160;
    val = (k < 148) ? src[k * 128 + j] : 0.f;
  } else if (i < 73728) {                // W2T edge MLPs, 128x128
    int t = i - 40960;
    const float* src = (t < 16384) ? ms_w2 : mv_w2;
    t &= 16383;
    int j = t >> 7, k = t & 127;
    val = src[k * 128 + j];
  } else if (i < 139264) {               // W1T node MLPs, K=256
    int t = i - 73728;
    const float* src = (t < 32768) ? us_w1 : uv_w1;
    t &= 32767;
    int j = t >> 8, k = t & 255;
    val = src[k * 128 + j];
  } else {                               // W2T node MLPs
    int t = i - 139264;
    const float* src = (t < 16384) ? us_w2 : uv_w2;
    t &= 16383;
    int j = t >> 7, k = t & 127;
    val = src[k * 128 + j];
  }
  wbuf[i] = f2bf(val);
}

// ---------------- prep: s -> bf16 ----------------------------------------------------
__global__ __launch_bounds__(256) void prep_s(
    const float* __restrict__ s, unsigned short* __restrict__ s_bf)
{
  int i = blockIdx.x * 256 + threadIdx.x;   // 320000 x float4
  if (i < 320000) {
    float4 p = *reinterpret_cast<const float4*>(s + i * 4);
    ushort4_t o;
    o[0] = f2bf(p.x); o[1] = f2bf(p.y); o[2] = f2bf(p.z); o[3] = f2bf(p.w);
    *reinterpret_cast<ushort4_t*>(s_bf + i * 4) = o;
  }
}

// ---------------- CSR build ----------------------------------------------------------
__global__ __launch_bounds__(256) void hist_kernel(
    const int* __restrict__ ecol, int* __restrict__ deg)
{
  int e = blockIdx.x * 256 + threadIdx.x;
  if (e < NEDGE) atomicAdd(&deg[ecol[e]], 1);
}

__global__ __launch_bounds__(256) void scan_kernel(
    const int* __restrict__ deg, int* __restrict__ offs)
{
  __shared__ int part[256];
  const int t = threadIdx.x;
  const int base = t * 40;
  int sum = 0;
  for (int i = 0; i < 40; ++i) {
    int idx = base + i;
    if (idx < NNODE) sum += deg[idx];
  }
  part[t] = sum;
  __syncthreads();
  for (int off = 1; off < 256; off <<= 1) {
    int vv = (t >= off) ? part[t - off] : 0;
    __syncthreads();
    if (t >= off) part[t] += vv;
    __syncthreads();
  }
  int run = (t == 0) ? 0 : part[t - 1];
  for (int i = 0; i < 40; ++i) {
    int idx = base + i;
    if (idx < NNODE) { offs[idx] = run; run += deg[idx]; }
  }
  if (t == 255) offs[NNODE] = run;
}

__global__ __launch_bounds__(256) void scatter_kernel(
    const int* __restrict__ ecol, const int* __restrict__ offs,
    int* __restrict__ cnt, int* __restrict__ eperm)
{
  int e = blockIdx.x * 256 + threadIdx.x;
  if (e < NEDGE) {
    int n = ecol[e];
    int p = atomicAdd(&cnt[n], 1);
    eperm[offs[n] + p] = e;
  }
}

// ---------------- shared MLP core (unchanged, verified) ------------------------------
__device__ __forceinline__ void run_mlp_edge(
    const short8 (&afrag)[2][5],
    const unsigned short* __restrict__ W1,
    const unsigned short* __restrict__ W2,
    const float* __restrict__ B1,
    unsigned short* hb, int g, int r16, f32x4 (&acc2)[2][8])
{
  f32x4 acc[2][8];
  const f32x4 z = {0.f, 0.f, 0.f, 0.f};
#pragma unroll
  for (int es = 0; es < 2; ++es)
#pragma unroll
    for (int nt = 0; nt < 8; ++nt) acc[es][nt] = z;
#pragma unroll
  for (int ks = 0; ks < 5; ++ks) {
#pragma unroll
    for (int nt = 0; nt < 8; ++nt) {
      const short8 w = *reinterpret_cast<const short8*>(W1 + (nt * 16 + r16) * K1PAD + ks * 32 + g * 8);
      acc[0][nt] = mfma16(afrag[0][ks], w, acc[0][nt]);
      acc[1][nt] = mfma16(afrag[1][ks], w, acc[1][nt]);
    }
  }
  float b1v[8];
#pragma unroll
  for (int nt = 0; nt < 8; ++nt) b1v[nt] = B1[nt * 16 + r16];
#pragma unroll
  for (int es = 0; es < 2; ++es)
#pragma unroll
    for (int nt = 0; nt < 8; ++nt)
#pragma unroll
      for (int r = 0; r < 4; ++r) {
        float p = acc[es][nt][r] + b1v[nt];
        hb[(es * 16 + g * 4 + r) * HSTR + nt * 16 + r16] = f2bf(silu(p));
      }
#pragma unroll
  for (int es = 0; es < 2; ++es)
#pragma unroll
    for (int nt = 0; nt < 8; ++nt) acc2[es][nt] = z;
#pragma unroll
  for (int ks = 0; ks < 4; ++ks) {
    const short8 a0 = *reinterpret_cast<const short8*>(hb + r16 * HSTR + ks * 32 + g * 8);
    const short8 a1 = *reinterpret_cast<const short8*>(hb + (16 + r16) * HSTR + ks * 32 + g * 8);
#pragma unroll
    for (int nt = 0; nt < 8; ++nt) {
      const short8 w = *reinterpret_cast<const short8*>(W2 + (nt * 16 + r16) * FDIM + ks * 32 + g * 8);
      acc2[0][nt] = mfma16(a0, w, acc2[0][nt]);
      acc2[1][nt] = mfma16(a1, w, acc2[1][nt]);
    }
  }
}

// ---------------- edge+aggregate: one wave per destination node ----------------------
__global__ __launch_bounds__(64) void edge_agg_kernel(
    const float* __restrict__ v,
    const int* __restrict__ erow, const float* __restrict__ rbf,
    const unsigned short* __restrict__ s_bf,
    const unsigned short* __restrict__ wms1, const unsigned short* __restrict__ wms2,
    const float* __restrict__ ms_b1, const float* __restrict__ ms_b2,
    const unsigned short* __restrict__ wmv1, const unsigned short* __restrict__ wmv2,
    const float* __restrict__ mv_b1, const float* __restrict__ mv_b2,
    const int* __restrict__ offs, const int* __restrict__ eperm,
    float* __restrict__ ds_agg, float* __restrict__ dv_agg)
{
  __shared__ unsigned short hb[32 * HSTR];   // 8704 B
  const int n = blockIdx.x;
  const int lane = threadIdx.x;
  const int g = lane >> 4, r16 = lane & 15;
  const int beg = offs[n], end = offs[n + 1];
  const int deg = end - beg;

  float dsT[8];
  float dvT0[8], dvT1[8], dvT2[8];
#pragma unroll
  for (int nt = 0; nt < 8; ++nt) { dsT[nt] = 0.f; dvT0[nt] = 0.f; dvT1[nt] = 0.f; dvT2[nt] = 0.f; }

  const float* vcn = v + (long)n * 384;

  for (int t0 = 0; t0 < deg; t0 += 32) {
    // ---- A fragments for this 32-edge tile (lane mapping: row = es*16 + r16) ----
    short8 afrag[2][5];
#pragma unroll
    for (int es = 0; es < 2; ++es) {
      int sidx = t0 + es * 16 + r16;
      if (sidx >= deg) sidx = deg - 1;           // clamp; masked at accumulation
      const int e = eperm[beg + sidx];
      const unsigned short* sp = s_bf + (long)erow[e] * FDIM + g * 8;
#pragma unroll
      for (int ks = 0; ks < 4; ++ks)
        afrag[es][ks] = *reinterpret_cast<const short8*>(sp + ks * 32);
      float xr[8] = {0.f, 0.f, 0.f, 0.f, 0.f, 0.f, 0.f, 0.f};
      if (g < 2) {
        float4 p0 = *reinterpret_cast<const float4*>(rbf + (long)e * 20 + g * 8);
        float4 p1 = *reinterpret_cast<const float4*>(rbf + (long)e * 20 + g * 8 + 4);
        xr[0] = p0.x; xr[1] = p0.y; xr[2] = p0.z; xr[3] = p0.w;
        xr[4] = p1.x; xr[5] = p1.y; xr[6] = p1.z; xr[7] = p1.w;
      } else if (g == 2) {
        float4 p0 = *reinterpret_cast<const float4*>(rbf + (long)e * 20 + 16);
        xr[0] = p0.x; xr[1] = p0.y; xr[2] = p0.z; xr[3] = p0.w;
      }
      afrag[es][4] = pack8(xr);
    }
    // epilogue slot ids: D rows map slot = es*16 + g*4 + r
    int rowE[2][4];
    bool okE[2][4];
#pragma unroll
    for (int es = 0; es < 2; ++es)
#pragma unroll
      for (int r = 0; r < 4; ++r) {
        int sidx = t0 + es * 16 + g * 4 + r;
        okE[es][r] = (sidx < deg);
        if (sidx >= deg) sidx = deg - 1;
        rowE[es][r] = erow[eperm[beg + sidx]];
      }

    // ---- ms MLP: accumulate raw acc2 (bias deferred as deg*b2) ----
    {
      f32x4 acc2[2][8];
      run_mlp_edge(afrag, wms1, wms2, ms_b1, hb, g, r16, acc2);
#pragma unroll
      for (int es = 0; es < 2; ++es)
#pragma unroll
        for (int r = 0; r < 4; ++r)
#pragma unroll
          for (int nt = 0; nt < 8; ++nt)
            dsT[nt] += okE[es][r] ? acc2[es][nt][r] : 0.f;
    }
    // ---- mv MLP: dv += (mlp+b2)/(|d|+eps) * d ----
    {
      f32x4 acc2[2][8];
      run_mlp_edge(afrag, wmv1, wmv2, mv_b1, hb, g, r16, acc2);
      float b2v[8];
#pragma unroll
      for (int nt = 0; nt < 8; ++nt) b2v[nt] = mv_b2[nt * 16 + r16];
#pragma unroll
      for (int es = 0; es < 2; ++es)
#pragma unroll
        for (int r = 0; r < 4; ++r) {
          const float* vr = v + (long)rowE[es][r] * 384;
          const bool ok = okE[es][r];
#pragma unroll
          for (int nt = 0; nt < 8; ++nt) {
            const int j = nt * 16 + r16;
            float d0 = vr[j]       - vcn[j];
            float d1 = vr[j + 128] - vcn[j + 128];
            float d2 = vr[j + 256] - vcn[j + 256];
            float nrm = sqrtf(d0 * d0 + d1 * d1 + d2 * d2);
            float base = (acc2[es][nt][r] + b2v[nt]) / (nrm + 1e-8f);
            if (ok) {
              dvT0[nt] += base * d0;
              dvT1[nt] += base * d1;
              dvT2[nt] += base * d2;
            }
          }
        }
    }
  }

  // ---- cross-g butterfly reduce (lanes xor 16, 32) ----
#pragma unroll
  for (int nt = 0; nt < 8; ++nt) {
    dsT[nt]  += __shfl_xor(dsT[nt], 16);  dsT[nt]  += __shfl_xor(dsT[nt], 32);
    dvT0[nt] += __shfl_xor(dvT0[nt], 16); dvT0[nt] += __shfl_xor(dvT0[nt], 32);
    dvT1[nt] += __shfl_xor(dvT1[nt], 16); dvT1[nt] += __shfl_xor(dvT1[nt], 32);
    dvT2[nt] += __shfl_xor(dvT2[nt], 16); dvT2[nt] += __shfl_xor(dvT2[nt], 32);
  }

  // ---- stores: g==0 -> ds (+deg*b2), g==1/2/3 -> dv k=0/1/2 ----
  if (g == 0) {
    const float fdeg = (float)deg;
#pragma unroll
    for (int nt = 0; nt < 8; ++nt)
      ds_agg[(long)n * FDIM + nt * 16 + r16] = dsT[nt] + fdeg * ms_b2[nt * 16 + r16];
  } else {
#pragma unroll
    for (int nt = 0; nt < 8; ++nt) {
      float val = (g == 1) ? dvT0[nt] : (g == 2) ? dvT1[nt] : dvT2[nt];
      dv_agg[(long)n * 384 + (g - 1) * 128 + nt * 16 + r16] = val;
    }
  }
}

// ---------------- node kernel: out = resid + MLP([xin | agg]), f32 store -------------
__global__ __launch_bounds__(256) void node_kernel(
    const float* __restrict__ xin,           // [rows][128] f32 (also residual)
    const float* __restrict__ agg,           // [rows][128] f32
    const unsigned short* __restrict__ W1T,  // [128][256] bf16
    const float* __restrict__ b1,
    const unsigned short* __restrict__ W2T,  // [128][128] bf16
    const float* __restrict__ b2,
    float* __restrict__ outp,                // [rows][128] f32
    int nrows)
{
  __shared__ unsigned short lds_h[4][32 * HSTR];
  const int tid = threadIdx.x;
  const int wid = tid >> 6, lane = tid & 63;
  const int g = lane >> 4, r16 = lane & 15;
  const int n0 = blockIdx.x * 128 + wid * 32;
  unsigned short* hb = &lds_h[wid][0];

  short8 afrag[2][8];
#pragma unroll
  for (int es = 0; es < 2; ++es) {
    int n = n0 + es * 16 + r16;
    if (n >= nrows) n = nrows - 1;
    const float* xp = xin + (long)n * FDIM + g * 8;
    const float* ap = agg + (long)n * FDIM + g * 8;
#pragma unroll
    for (int ks = 0; ks < 4; ++ks) {
      float4 p0 = *reinterpret_cast<const float4*>(xp + ks * 32);
      float4 p1 = *reinterpret_cast<const float4*>(xp + ks * 32 + 4);
      afrag[es][ks] = cvt8(p0, p1);
    }
#pragma unroll
    for (int ks = 0; ks < 4; ++ks) {
      float4 p0 = *reinterpret_cast<const float4*>(ap + ks * 32);
      float4 p1 = *reinterpret_cast<const float4*>(ap + ks * 32 + 4);
      afrag[es][4 + ks] = cvt8(p0, p1);
    }
  }
  f32x4 acc[2][8];
  const f32x4 z = {0.f, 0.f, 0.f, 0.f};
#pragma unroll
  for (int es = 0; es < 2; ++es)
#pragma unroll
    for (int nt = 0; nt < 8; ++nt) acc[es][nt] = z;
#pragma unroll
  for (int ks = 0; ks < 8; ++ks) {
#pragma unroll
    for (int nt = 0; nt < 8; ++nt) {
      const short8 w = *reinterpret_cast<const short8*>(W1T + (nt * 16 + r16) * 256 + ks * 32 + g * 8);
      acc[0][nt] = mfma16(afrag[0][ks], w, acc[0][nt]);
      acc[1][nt] = mfma16(afrag[1][ks], w, acc[1][nt]);
    }
  }
  float b1v[8];
#pragma unroll
  for (int nt = 0; nt < 8; ++nt) b1v[nt] = b1[nt * 16 + r16];
#pragma unroll
  for (int es = 0; es < 2; ++es)
#pragma unroll
    for (int nt = 0; nt < 8; ++nt)
#pragma unroll
      for (int r = 0; r < 4; ++r) {
        float p = acc[es][nt][r] + b1v[nt];
        hb[(es * 16 + g * 4 + r) * HSTR + nt * 16 + r16] = f2bf(silu(p));
      }
  f32x4 acc2[2][8];
#pragma unroll
  for (int es = 0; es < 2; ++es)
#pragma unroll
    for (int nt = 0; nt < 8; ++nt) acc2[es][nt] = z;
#pragma unroll
  for (int ks = 0; ks < 4; ++ks) {
    const short8 a0 = *reinterpret_cast<const short8*>(hb + r16 * HSTR + ks * 32 + g * 8);
    const short8 a1 = *reinterpret_cast<const short8*>(hb + (16 + r16) * HSTR + ks * 32 + g * 8);
#pragma unroll
    for (int nt = 0; nt < 8; ++nt) {
      const short8 w = *reinterpret_cast<const short8*>(W2T + (nt * 16 + r16) * FDIM + ks * 32 + g * 8);
      acc2[0][nt] = mfma16(a0, w, acc2[0][nt]);
      acc2[1][nt] = mfma16(a1, w, acc2[1][nt]);
    }
  }
  float b2v[8];
#pragma unroll
  for (int nt = 0; nt < 8; ++nt) b2v[nt] = b2[nt * 16 + r16];
#pragma unroll
  for (int es = 0; es < 2; ++es)
#pragma unroll
    for (int r = 0; r < 4; ++r) {
      const int n = n0 + es * 16 + g * 4 + r;
      if (n < nrows) {
#pragma unroll
        for (int nt = 0; nt < 8; ++nt) {
          const int j = nt * 16 + r16;
          outp[(long)n * FDIM + j] = xin[(long)n * FDIM + j] + acc2[es][nt][r] + b2v[nt];
        }
      }
    }
}

extern "C" void kernel_launch(void* const* d_in, const int* in_sizes, int n_in,
                              void* d_out, int out_size, void* d_ws, size_t ws_size,
                              hipStream_t stream) {
  const float* s     = (const float*)d_in[0];
  const float* v     = (const float*)d_in[1];
  const int*   eidx  = (const int*)d_in[2];
  const float* rbf   = (const float*)d_in[3];
  const float* ms_w1 = (const float*)d_in[4];  const float* ms_b1 = (const float*)d_in[5];
  const float* ms_w2 = (const float*)d_in[6];  const float* ms_b2 = (const float*)d_in[7];
  const float* mv_w1 = (const float*)d_in[8];  const float* mv_b1 = (const float*)d_in[9];
  const float* mv_w2 = (const float*)d_in[10]; const float* mv_b2 = (const float*)d_in[11];
  const float* us_w1 = (const float*)d_in[12]; const float* us_b1 = (const float*)d_in[13];
  const float* us_w2 = (const float*)d_in[14]; const float* us_b2 = (const float*)d_in[15];
  const float* uv_w1 = (const float*)d_in[16]; const float* uv_b1 = (const float*)d_in[17];
  const float* uv_w2 = (const float*)d_in[18]; const float* uv_b2 = (const float*)d_in[19];

  char* ws = (char*)d_ws;
  float* ds_agg = (float*)(ws);                                // 5.12 MB
  float* dv_agg = (float*)(ws + 5120000);                      // 15.36 MB
  unsigned short* s_bf = (unsigned short*)(ws + 20480000);     // 2.56 MB
  unsigned short* wbuf = (unsigned short*)(ws + 23040000);     // 344,064 B
  int* deg   = (int*)(ws + 23384064);                          // 40 KB
  int* cnt   = (int*)(ws + 23424064);                          // 40 KB
  int* offs  = (int*)(ws + 23464064);                          // 40,004 B
  int* eperm = (int*)(ws + 23504068);                          // 2.56 MB

  const int* ecol = eidx + NEDGE;

  hipMemsetAsync(deg, 0, 80000, stream);  // deg + cnt contiguous

  prep_wt<<<672, 256, 0, stream>>>(ms_w1, mv_w1, ms_w2, mv_w2,
                                   us_w1, uv_w1, us_w2, uv_w2, wbuf);
  prep_s<<<1250, 256, 0, stream>>>(s, s_bf);
  hist_kernel<<<2500, 256, 0, stream>>>(ecol, deg);
  scan_kernel<<<1, 256, 0, stream>>>(deg, offs);
  scatter_kernel<<<2500, 256, 0, stream>>>(ecol, offs, cnt, eperm);

  edge_agg_kernel<<<NNODE, 64, 0, stream>>>(
      v, eidx, rbf, s_bf,
      wbuf + 0,     wbuf + 40960, ms_b1, ms_b2,
      wbuf + 20480, wbuf + 57344, mv_b1, mv_b2,
      offs, eperm, ds_agg, dv_agg);

  float* outp = (float*)d_out;
  node_kernel<<<79, 256, 0, stream>>>(s, ds_agg, wbuf + 73728, us_b1,
                                      wbuf + 139264, us_b2, outp, NNODE);
  node_kernel<<<235, 256, 0, stream>>>(v, dv_agg, wbuf + 106496, uv_b1,
                                       wbuf + 155648, uv_b2, outp + NNODE * FDIM, 3 * NNODE);
}